// Round 8
// baseline (150.758 us; speedup 1.0000x reference)
//
#include <hip/hip_runtime.h>
#include <hip/hip_bf16.h>

#define NN 50000
#define FF 128
#define UU 128
#define NREL 8
#define NE 60000
#define NKEY (NREL * NN)        // 400000
#define NET (NREL * NE)         // 480000

typedef __attribute__((ext_vector_type(8))) short bf16x8;
typedef __attribute__((ext_vector_type(4))) float f32x4;

// ---------------- prep: X->bf16, W->fragment-layout bf16 ----------------
// Wf layout: for (m,c,s), a 1KB block at ((m*8+c)*4+s)*512 ushorts; lane
// (ag*16+al) holds 8 bf16 of W_m[k = s*32+ag*8+j][col = c*16+al], j=0..7.
// Every B-frag load in gemm is then one coalesced 1KB dwordx4.

__global__ __launch_bounds__(256) void prep_kernel(
    const float* __restrict__ X, const float* __restrict__ Wself,
    const float* __restrict__ Wrel, ushort* __restrict__ Xb,
    ushort* __restrict__ Wf)
{
    int i = blockIdx.x * 256 + threadIdx.x;
    if (i < NN * FF / 4) {                      // X -> bf16
        float4 v = ((const float4*)X)[i];
        union { __hip_bfloat162 h[2]; uint2 u; } p;
        p.h[0] = __float22bfloat162_rn(make_float2(v.x, v.y));
        p.h[1] = __float22bfloat162_rn(make_float2(v.z, v.w));
        ((uint2*)Xb)[i] = p.u;
    }
    if (i < 9 * FF * UU) {                      // W -> fragment layout
        int m = i >> 14, k = (i >> 7) & 127, col = i & 127;
        int c = col >> 4, al = col & 15;
        int s = k >> 5, ag = (k >> 3) & 3, j = k & 7;
        float v = (m == 0) ? Wself[i] : Wrel[i - FF * UU];
        __hip_bfloat16 h = __float2bfloat16(v);
        Wf[((m * 8 + c) * 4 + s) * 512 + (ag * 16 + al) * 8 + j] = *(ushort*)&h;
    }
}

// ---------------- per-(rel,dst) linked list with packed records ----------------
// rec[i] = {src, w_bits, next, 0} -> one 16B broadcast gather per edge in agg.

__global__ __launch_bounds__(256) void build_kernel(
    const int* __restrict__ esrc, const int* __restrict__ edst,
    const float* __restrict__ ew, int* __restrict__ head, int4* __restrict__ rec)
{
    int i = blockIdx.x * 256 + threadIdx.x;
    if (i < NET) {
        int key = (i / NE) * NN + edst[i];      // const divisor -> magic mul
        int prev = atomicExch(&head[key], i);
        rec[i] = make_int4(esrc[i], __float_as_int(ew[i]), prev, 0);
    }
}

// ---------------- pass 1: aggregation, one half-wave (32 lanes) per key ----------
// Zb[key][0:128) = bf16( sum w * X[src] ); zeros if list empty.

__global__ __launch_bounds__(256) void agg_kernel(
    const ushort* __restrict__ Xb, const int* __restrict__ head,
    const int4* __restrict__ rec, ushort* __restrict__ Zb)
{
    const int key = blockIdx.x * 8 + (threadIdx.x >> 5);
    const int l = threadIdx.x & 31;             // lane handles elements 4l..4l+3
    float a0 = 0.f, a1 = 0.f, a2 = 0.f, a3 = 0.f;
    int e = head[key];
    while (e >= 0) {
        int4 r = rec[e];                        // broadcast within half-wave
        float w = __int_as_float(r.y);
        uint2 x = *(const uint2*)(Xb + (size_t)r.x * FF + 4 * l);
        a0 = fmaf(__uint_as_float(x.x << 16), w, a0);
        a1 = fmaf(__uint_as_float(x.x & 0xffff0000u), w, a1);
        a2 = fmaf(__uint_as_float(x.y << 16), w, a2);
        a3 = fmaf(__uint_as_float(x.y & 0xffff0000u), w, a3);
        e = r.z;
    }
    union { __hip_bfloat162 h[2]; uint2 u; } p;
    p.h[0] = __float22bfloat162_rn(make_float2(a0, a1));
    p.h[1] = __float22bfloat162_rn(make_float2(a2, a3));
    *(uint2*)(Zb + (size_t)key * FF + 4 * l) = p.u;
}

// ---------------- pass 2: GEMM, 4 waves per 16-row tile, m-split ----------------
// Wave w computes acc over matrices m = w, w+4, w+8 (<9); waves 1-3 dump acc to
// LDS (XOR-swizzled slots to dodge the 128B-stride bank conflict), wave 0
// reduces + bias + relu + store. A-frag: lane al -> row R0+al, k-group ag,
// contiguous short8. B-frag: one coalesced 1KB load per (m,c,s) from Wf.
// D: col = c*16+al, row = R0 + ag*4 + q (layout verified rounds 5-7).

__global__ __launch_bounds__(256, 4) void gemm_kernel(
    const ushort* __restrict__ Xb, const ushort* __restrict__ Zb,
    const ushort* __restrict__ Wf, const float* __restrict__ bias,
    float* __restrict__ out)
{
    __shared__ f32x4 red[3 * 512];              // 24 KB
    const int R0 = blockIdx.x * 16;
    const int wid = threadIdx.x >> 6;
    const int lane = threadIdx.x & 63;
    const int al = lane & 15;
    const int ag = lane >> 4;

    f32x4 acc[8];
    #pragma unroll
    for (int c = 0; c < 8; ++c) acc[c] = (f32x4){0.f, 0.f, 0.f, 0.f};

    const bf16x8* Wf8 = (const bf16x8*)Wf;

    #pragma unroll
    for (int mm = 0; mm < 3; ++mm) {
        const int m = wid + mm * 4;             // wave-uniform
        if (m < 9) {
            const ushort* Arow = (m == 0)
                ? Xb + (size_t)(R0 + al) * FF
                : Zb + ((size_t)(m - 1) * NN + R0 + al) * FF;
            bf16x8 afr[4];
            #pragma unroll
            for (int s = 0; s < 4; ++s)
                afr[s] = *(const bf16x8*)(Arow + s * 32 + ag * 8);
            #pragma unroll
            for (int c = 0; c < 8; ++c) {
                #pragma unroll
                for (int s = 0; s < 4; ++s) {
                    bf16x8 bfr = Wf8[((m * 8 + c) * 4 + s) * 64 + lane];
                    acc[c] = __builtin_amdgcn_mfma_f32_16x16x32_bf16(
                        afr[s], bfr, acc[c], 0, 0, 0);
                }
            }
        }
    }

    if (wid > 0) {
        f32x4* slot = red + (wid - 1) * 512 + lane * 8;
        #pragma unroll
        for (int c = 0; c < 8; ++c) slot[c ^ (lane & 7)] = acc[c];
    }
    __syncthreads();
    if (wid == 0) {
        #pragma unroll
        for (int w = 0; w < 3; ++w) {
            const f32x4* slot = red + w * 512 + lane * 8;
            #pragma unroll
            for (int c = 0; c < 8; ++c) acc[c] += slot[c ^ (lane & 7)];
        }
        #pragma unroll
        for (int c = 0; c < 8; ++c) {
            int col = c * 16 + al;
            float b = bias[col];
            #pragma unroll
            for (int q = 0; q < 4; ++q) {
                int row = R0 + ag * 4 + q;
                out[(size_t)row * UU + col] = fmaxf(acc[c][q] + b, 0.f);
            }
        }
    }
}

// ---------------- launch ----------------

extern "C" void kernel_launch(void* const* d_in, const int* in_sizes, int n_in,
                              void* d_out, int out_size, void* d_ws, size_t ws_size,
                              hipStream_t stream) {
    const float* X     = (const float*)d_in[0];
    const int*   esrc  = (const int*)d_in[1];
    const int*   edst  = (const int*)d_in[2];
    const float* ew    = (const float*)d_in[3];
    const float* Wself = (const float*)d_in[4];
    const float* Wrel  = (const float*)d_in[5];
    const float* bias  = (const float*)d_in[6];
    float* out = (float*)d_out;

    // ws layout (16B-aligned segments), ~125 MB total
    ushort* Zb   = (ushort*)d_ws;               // NKEY*FF bf16 = 102.4 MB
    ushort* Xb   = Zb + (size_t)NKEY * FF;      // NN*FF bf16   = 12.8 MB
    ushort* Wf   = Xb + (size_t)NN * FF;        // 9*FF*UU bf16 = 0.29 MB
    int*    head = (int*)(Wf + 9 * FF * UU);    // NKEY         = 1.6 MB
    int4*   rec  = (int4*)(head + NKEY);        // NET int4     = 7.7 MB

    hipMemsetAsync(head, 0xFF, NKEY * sizeof(int), stream);   // head = -1
    hipLaunchKernelGGL(prep_kernel,  dim3(NN * FF / 4 / 256), dim3(256), 0, stream,
                       X, Wself, Wrel, Xb, Wf);
    hipLaunchKernelGGL(build_kernel, dim3((NET + 255) / 256), dim3(256), 0, stream,
                       esrc, edst, ew, head, rec);
    hipLaunchKernelGGL(agg_kernel,   dim3(NKEY / 8), dim3(256), 0, stream,
                       Xb, head, rec, Zb);
    hipLaunchKernelGGL(gemm_kernel,  dim3(NN / 16), dim3(256), 0, stream,
                       Xb, Zb, Wf, bias, out);
}

// Round 9
// 148.842 us; speedup vs baseline: 1.0129x; 1.0129x over previous
//
#include <hip/hip_runtime.h>
#include <hip/hip_bf16.h>

#define NN 50000
#define FF 128
#define UU 128
#define NREL 8
#define NE 60000
#define NKEY (NREL * NN)        // 400000
#define NET (NREL * NE)         // 480000

typedef __attribute__((ext_vector_type(8))) short bf16x8;
typedef __attribute__((ext_vector_type(4))) float f32x4;

// ---------------- prep: X->bf16, W->fragment-layout bf16 ----------------
// Wf layout: for (m,c,s), a 1KB block at ((m*8+c)*4+s)*512 ushorts; lane
// (ag*16+al) holds 8 bf16 of W_m[k = s*32+ag*8+j][col = c*16+al], j=0..7.
// Every B-frag load in gemm is then one coalesced 1KB dwordx4.

__global__ __launch_bounds__(256) void prep_kernel(
    const float* __restrict__ X, const float* __restrict__ Wself,
    const float* __restrict__ Wrel, ushort* __restrict__ Xb,
    ushort* __restrict__ Wf)
{
    int i = blockIdx.x * 256 + threadIdx.x;
    if (i < NN * FF / 4) {                      // X -> bf16
        float4 v = ((const float4*)X)[i];
        union { __hip_bfloat162 h[2]; uint2 u; } p;
        p.h[0] = __float22bfloat162_rn(make_float2(v.x, v.y));
        p.h[1] = __float22bfloat162_rn(make_float2(v.z, v.w));
        ((uint2*)Xb)[i] = p.u;
    }
    if (i < 9 * FF * UU) {                      // W -> fragment layout
        int m = i >> 14, k = (i >> 7) & 127, col = i & 127;
        int c = col >> 4, al = col & 15;
        int s = k >> 5, ag = (k >> 3) & 3, j = k & 7;
        float v = (m == 0) ? Wself[i] : Wrel[i - FF * UU];
        __hip_bfloat16 h = __float2bfloat16(v);
        Wf[((m * 8 + c) * 4 + s) * 512 + (ag * 16 + al) * 8 + j] = *(ushort*)&h;
    }
}

// ---------------- per-(rel,dst) linked list with packed records ----------------

__global__ __launch_bounds__(256) void build_kernel(
    const int* __restrict__ esrc, const int* __restrict__ edst,
    const float* __restrict__ ew, int* __restrict__ head, int4* __restrict__ rec)
{
    int i = blockIdx.x * 256 + threadIdx.x;
    if (i < NET) {
        int key = (i / NE) * NN + edst[i];      // const divisor -> magic mul
        int prev = atomicExch(&head[key], i);
        rec[i] = make_int4(esrc[i], __float_as_int(ew[i]), prev, 0);
    }
}

// ---------------- pass 1: aggregation, one wave per 4 consecutive keys ----------
// Zb[key][0:128) = bf16( sum w * X[src] ); zeros if list empty. Lane l owns
// elements 2l, 2l+1. Heads + root recs prefetched for all 4 keys, then each
// walk issues next-rec before its FMAs so X-load and rec-load overlap.

#define AGG_WALK(e, r, ax, ay)                                              \
    while (e >= 0) {                                                        \
        float w = __int_as_float(r.y);                                      \
        uint x = *(const uint*)(Xb + (size_t)r.x * FF + 2 * l);             \
        e = r.z;                                                            \
        if (e >= 0) r = rec[e];                                             \
        ax = fmaf(__uint_as_float(x << 16), w, ax);                         \
        ay = fmaf(__uint_as_float(x & 0xffff0000u), w, ay);                 \
    }

__global__ __launch_bounds__(256) void agg_kernel(
    const ushort* __restrict__ Xb, const int* __restrict__ head,
    const int4* __restrict__ rec, ushort* __restrict__ Zb)
{
    const int k0 = (blockIdx.x * 4 + (threadIdx.x >> 6)) * 4;
    const int l = threadIdx.x & 63;

    float a0x = 0.f, a0y = 0.f, a1x = 0.f, a1y = 0.f;
    float a2x = 0.f, a2y = 0.f, a3x = 0.f, a3y = 0.f;

    int e0 = head[k0 + 0], e1 = head[k0 + 1];
    int e2 = head[k0 + 2], e3 = head[k0 + 3];
    int4 r0, r1, r2, r3;
    if (e0 >= 0) r0 = rec[e0];
    if (e1 >= 0) r1 = rec[e1];
    if (e2 >= 0) r2 = rec[e2];
    if (e3 >= 0) r3 = rec[e3];

    AGG_WALK(e0, r0, a0x, a0y)
    AGG_WALK(e1, r1, a1x, a1y)
    AGG_WALK(e2, r2, a2x, a2y)
    AGG_WALK(e3, r3, a3x, a3y)

    __hip_bfloat162 h;
    h = __float22bfloat162_rn(make_float2(a0x, a0y));
    *(uint*)(Zb + (size_t)(k0 + 0) * FF + 2 * l) = *(uint*)&h;
    h = __float22bfloat162_rn(make_float2(a1x, a1y));
    *(uint*)(Zb + (size_t)(k0 + 1) * FF + 2 * l) = *(uint*)&h;
    h = __float22bfloat162_rn(make_float2(a2x, a2y));
    *(uint*)(Zb + (size_t)(k0 + 2) * FF + 2 * l) = *(uint*)&h;
    h = __float22bfloat162_rn(make_float2(a3x, a3y));
    *(uint*)(Zb + (size_t)(k0 + 3) * FF + 2 * l) = *(uint*)&h;
}

// ---------------- pass 2: GEMM, one independent wave per 16 output rows --------
// No LDS, no barriers. Fully unrolled m-loop (static Wf offsets) + high VGPR
// budget so B-loads pipeline. A-frag: lane al -> row R0+al, k-group ag,
// contiguous short8. B-frag: one coalesced 1KB load per (m,c,s), L1/L2-hot
// (all waves sweep the same 294KB Wf). D: col=c*16+al, row=R0+ag*4+q.

__global__ __launch_bounds__(256, 3) void gemm_kernel(
    const ushort* __restrict__ Xb, const ushort* __restrict__ Zb,
    const ushort* __restrict__ Wf, const float* __restrict__ bias,
    float* __restrict__ out)
{
    const int gwid = blockIdx.x * 4 + (threadIdx.x >> 6);
    if (gwid >= NN / 16) return;
    const int R0 = gwid * 16;
    const int lane = threadIdx.x & 63;
    const int al = lane & 15;
    const int ag = lane >> 4;

    f32x4 acc[8];
    #pragma unroll
    for (int c = 0; c < 8; ++c) acc[c] = (f32x4){0.f, 0.f, 0.f, 0.f};

    const bf16x8* Wf8 = (const bf16x8*)Wf;

    #pragma unroll
    for (int m = 0; m < 9; ++m) {
        const ushort* Arow = (m == 0)
            ? Xb + (size_t)(R0 + al) * FF
            : Zb + ((size_t)(m - 1) * NN + R0 + al) * FF;
        bf16x8 a0 = *(const bf16x8*)(Arow + 0 * 32 + ag * 8);
        bf16x8 a1 = *(const bf16x8*)(Arow + 1 * 32 + ag * 8);
        bf16x8 a2 = *(const bf16x8*)(Arow + 2 * 32 + ag * 8);
        bf16x8 a3 = *(const bf16x8*)(Arow + 3 * 32 + ag * 8);
        #pragma unroll
        for (int c = 0; c < 8; ++c) {
            acc[c] = __builtin_amdgcn_mfma_f32_16x16x32_bf16(
                a0, Wf8[((m * 8 + c) * 4 + 0) * 64 + lane], acc[c], 0, 0, 0);
            acc[c] = __builtin_amdgcn_mfma_f32_16x16x32_bf16(
                a1, Wf8[((m * 8 + c) * 4 + 1) * 64 + lane], acc[c], 0, 0, 0);
            acc[c] = __builtin_amdgcn_mfma_f32_16x16x32_bf16(
                a2, Wf8[((m * 8 + c) * 4 + 2) * 64 + lane], acc[c], 0, 0, 0);
            acc[c] = __builtin_amdgcn_mfma_f32_16x16x32_bf16(
                a3, Wf8[((m * 8 + c) * 4 + 3) * 64 + lane], acc[c], 0, 0, 0);
        }
    }

    #pragma unroll
    for (int c = 0; c < 8; ++c) {
        int col = c * 16 + al;
        float b = bias[col];
        #pragma unroll
        for (int q = 0; q < 4; ++q) {
            int row = R0 + ag * 4 + q;
            out[(size_t)row * UU + col] = fmaxf(acc[c][q] + b, 0.f);
        }
    }
}

// ---------------- launch ----------------

extern "C" void kernel_launch(void* const* d_in, const int* in_sizes, int n_in,
                              void* d_out, int out_size, void* d_ws, size_t ws_size,
                              hipStream_t stream) {
    const float* X     = (const float*)d_in[0];
    const int*   esrc  = (const int*)d_in[1];
    const int*   edst  = (const int*)d_in[2];
    const float* ew    = (const float*)d_in[3];
    const float* Wself = (const float*)d_in[4];
    const float* Wrel  = (const float*)d_in[5];
    const float* bias  = (const float*)d_in[6];
    float* out = (float*)d_out;

    // ws layout (16B-aligned segments), ~125 MB total
    ushort* Zb   = (ushort*)d_ws;               // NKEY*FF bf16 = 102.4 MB
    ushort* Xb   = Zb + (size_t)NKEY * FF;      // NN*FF bf16   = 12.8 MB
    ushort* Wf   = Xb + (size_t)NN * FF;        // 9*FF*UU bf16 = 0.29 MB
    int*    head = (int*)(Wf + 9 * FF * UU);    // NKEY         = 1.6 MB
    int4*   rec  = (int4*)(head + NKEY);        // NET int4     = 7.7 MB

    hipMemsetAsync(head, 0xFF, NKEY * sizeof(int), stream);   // head = -1
    hipLaunchKernelGGL(prep_kernel,  dim3(NN * FF / 4 / 256), dim3(256), 0, stream,
                       X, Wself, Wrel, Xb, Wf);
    hipLaunchKernelGGL(build_kernel, dim3((NET + 255) / 256), dim3(256), 0, stream,
                       esrc, edst, ew, head, rec);
    hipLaunchKernelGGL(agg_kernel,   dim3(NKEY / 16), dim3(256), 0, stream,
                       Xb, head, rec, Zb);
    hipLaunchKernelGGL(gemm_kernel,  dim3((NN / 16 + 3) / 4), dim3(256), 0, stream,
                       Xb, Zb, Wf, bias, out);
}